// Round 2
// baseline (311.411 us; speedup 1.0000x reference)
//
#include <hip/hip_runtime.h>
#include <cstdint>
#include <cstddef>

#define B_ROWS 16384
#define D_DIM  1024
#define F_REAL 1034          // real hidden/feature dim
#define N_PAD  1152          // 9 * 128
#define K_PAD  1088          // 1024 h + 10 scal + 54 zero  (17 * 64)
#define NKT    34            // K-steps of BK=32
#define EPSN   1e-12f

typedef __bf16 bf16x8 __attribute__((ext_vector_type(8)));
typedef float  f32x4  __attribute__((ext_vector_type(4)));
typedef unsigned short u16;

__device__ __forceinline__ u16 f2bf(float f) {
    __bf16 b = (__bf16)f;
    return __builtin_bit_cast(u16, b);
}

// -------------------------------------------------------------------------
// prep R2: persistent waves. R0/R1 diagnosis: Occ 57% with NO resource cap
// + VALUBusy 13% + HBM 21% = short-block churn, per-row latency exposed.
// Now: 1024 blocks (exactly 4/CU), 1 full row per wave, 4 rows per wave,
// depth-2 load pipeline (next row's 12 loads in flight during current row's
// reduce), nd + s_nn hoisted out of the row loop. No LDS, no barriers.
// -------------------------------------------------------------------------
__global__ __launch_bounds__(256)
void prep_kernel(const float* __restrict__ h, const float* __restrict__ vp,
                 const float* __restrict__ vh, const float* __restrict__ nd,
                 const float* __restrict__ nsp, u16* __restrict__ A)
{
    const int tid  = threadIdx.x;
    const int lane = tid & 63;
    const int wg   = blockIdx.x * 4 + (tid >> 6);   // 0..4095
    const int r0   = wg * 4;

    const float4* ndp = (const float4*)nd;
    float4 n[4];
    #pragma unroll
    for (int c = 0; c < 4; ++c) n[c] = ndp[lane + c * 64];
    const float ns = nsp[0];

    float s_nn = 0.f;
    #pragma unroll
    for (int c = 0; c < 4; ++c)
        s_nn += n[c].x*n[c].x + n[c].y*n[c].y + n[c].z*n[c].z + n[c].w*n[c].w;
    #pragma unroll
    for (int m = 32; m >= 1; m >>= 1) s_nn += __shfl_xor(s_nn, m, 64);
    const float nnc = fmaxf(sqrtf(s_nn), EPSN);

    float4 P[2][4], Q[2][4], F[2][4];

#define LOADR(st, r)                                                          \
    do {                                                                      \
        const float4* vpp = (const float4*)(vp + (size_t)(r) * D_DIM);        \
        const float4* vhp = (const float4*)(vh + (size_t)(r) * D_DIM);        \
        const float4* hp  = (const float4*)(h  + (size_t)(r) * D_DIM);        \
        _Pragma("unroll")                                                     \
        for (int c = 0; c < 4; ++c) P[st][c] = vpp[lane + c * 64];            \
        _Pragma("unroll")                                                     \
        for (int c = 0; c < 4; ++c) Q[st][c] = vhp[lane + c * 64];            \
        _Pragma("unroll")                                                     \
        for (int c = 0; c < 4; ++c) F[st][c] = hp[lane + c * 64];             \
    } while (0)

    LOADR(0, r0);
    #pragma unroll
    for (int i = 0; i < 4; ++i) {
        const int st = i & 1;
        if (i + 1 < 4) LOADR(((i + 1) & 1), r0 + i + 1);
        __builtin_amdgcn_sched_barrier(0);   // keep next-row loads above use

        float s_pp = 0.f, s_hh = 0.f, s_pv = 0.f, s_ff = 0.f;
        float s_dd = 0.f, s_pn = 0.f, s_hn = 0.f;
        #pragma unroll
        for (int c = 0; c < 4; ++c) {
            float4 p = P[st][c], q = Q[st][c], f = F[st][c], nn = n[c];
            s_pp += p.x*p.x + p.y*p.y + p.z*p.z + p.w*p.w;
            s_hh += q.x*q.x + q.y*q.y + q.z*q.z + q.w*q.w;
            s_pv += p.x*q.x + p.y*q.y + p.z*q.z + p.w*q.w;
            s_ff += f.x*f.x + f.y*f.y + f.z*f.z + f.w*f.w;
            float dx = q.x-p.x, dy = q.y-p.y, dz = q.z-p.z, dw = q.w-p.w;
            s_dd += dx*dx + dy*dy + dz*dz + dw*dw;
            s_pn += p.x*nn.x + p.y*nn.y + p.z*nn.z + p.w*nn.w;
            s_hn += q.x*nn.x + q.y*nn.y + q.z*nn.z + q.w*nn.w;
        }

        u16* arow = A + (size_t)(r0 + i) * K_PAD;
        #pragma unroll
        for (int c = 0; c < 4; ++c) {
            ushort4 hc;
            hc.x = f2bf(F[st][c].x); hc.y = f2bf(F[st][c].y);
            hc.z = f2bf(F[st][c].z); hc.w = f2bf(F[st][c].w);
            *(ushort4*)(arow + (lane + c * 64) * 4) = hc;
        }

        #pragma unroll
        for (int m = 32; m >= 1; m >>= 1) {
            s_pp += __shfl_xor(s_pp, m, 64);
            s_hh += __shfl_xor(s_hh, m, 64);
            s_pv += __shfl_xor(s_pv, m, 64);
            s_ff += __shfl_xor(s_ff, m, 64);
            s_dd += __shfl_xor(s_dd, m, 64);
            s_pn += __shfl_xor(s_pn, m, 64);
            s_hn += __shfl_xor(s_hn, m, 64);
        }

        if (lane == 0) {
            float np_ = sqrtf(s_pp), nh_ = sqrtf(s_hh), nf = sqrtf(s_ff);
            float npc = fmaxf(np_, EPSN), nhc = fmaxf(nh_, EPSN);
            float align = s_pv / (npc * nhc);
            u16 fo[64];
            fo[0] = f2bf(align);
            fo[1] = f2bf(-align);
            fo[2] = f2bf(0.5f * (1.0f + align));      // K_O = 1
            fo[3] = f2bf(0.5f * (1.0f - align));
            fo[4] = f2bf(sqrtf(s_dd));
            fo[5] = f2bf(np_);
            fo[6] = f2bf(nh_);
            fo[7] = f2bf(nf);
            fo[8] = f2bf(ns * s_pn / (npc * nnc));
            fo[9] = f2bf(ns * s_hn / (nhc * nnc));
            #pragma unroll
            for (int k = 10; k < 64; ++k) fo[k] = 0;
            #pragma unroll
            for (int k = 0; k < 8; ++k)
                *(uint4*)(arow + D_DIM + k * 8) = *(uint4*)(fo + k * 8);
        }
    }
#undef LOADR
}

// -------------------------------------------------------------------------
// w1 [1034x1034] f32 -> padded bf16 B^T matrix [1152 x 1088]
// -------------------------------------------------------------------------
__global__ __launch_bounds__(256)
void convw_kernel(const float* __restrict__ w1, u16* __restrict__ Bm)
{
    const int i = blockIdx.x;
    for (int j = threadIdx.x; j < K_PAD; j += 256) {
        float v = (i < F_REAL && j < F_REAL) ? w1[(size_t)i * F_REAL + j] : 0.0f;
        Bm[(size_t)i * K_PAD + j] = f2bf(v);
    }
}

// out[b*3+c] = b2[c]  (out is poisoned 0xAA each launch)
__global__ __launch_bounds__(256)
void initout_kernel(const float* __restrict__ b2, float* __restrict__ out)
{
    int i = blockIdx.x * 256 + threadIdx.x;
    if (i < B_ROWS * 3) out[i] = b2[i % 3];
}

// -------------------------------------------------------------------------
// GEMM1 R2: m97 structure. 128x128 tile, 4 waves (64x64 each), BK=32,
// DOUBLE-BUFFERED LDS (2x16KB=32KB -> 5 blocks/CU) staged via async
// global_load_lds width=16 (no register staging, no WRITE phase, ONE
// barrier per K-step). R1 diagnosis: reg-staging pushed unified regs to
// ~256/wave -> 2 waves/SIMD -> latency-bound at MfmaUtil 19%.
// Swizzle (measured conflict-free): LDS slot (row, c) holds global chunk
// c ^ ((row>>1)&3); linear gld dest + inverse-swizzled SOURCE + swizzled
// ds_read (rule 21). Fused bias+ReLU+GEMM2 epilogue -> atomic partials.
// -------------------------------------------------------------------------
__global__ __launch_bounds__(256)
void gemm_kernel(const u16* __restrict__ A,
                 const u16* __restrict__ Bm,
                 const float* __restrict__ b1, const float* __restrict__ w2,
                 float* __restrict__ out)
{
    __shared__ __bf16 As[2 * 128 * 32];   // 16 KB (2 buffers)
    __shared__ __bf16 Bs[2 * 128 * 32];   // 16 KB

    const int tid  = threadIdx.x;
    const int lane = tid & 63;
    const int wave = tid >> 6;
    const int wm = wave >> 1, wn = wave & 1;   // wave covers 64(m) x 64(n)
    const int bm = blockIdx.x, bn = blockIdx.y;

    // staging: slot s = l*256 + tid; row = s>>2; src chunk = (s&3)^((s>>3)&3)
    const u16* srcA[2];
    const u16* srcB[2];
    #pragma unroll
    for (int l = 0; l < 2; ++l) {
        int s   = l * 256 + tid;
        int row = s >> 2;
        int c   = (s & 3) ^ ((s >> 3) & 3);
        srcA[l] = A  + (size_t)(bm * 128 + row) * K_PAD + c * 8;
        srcB[l] = Bm + (size_t)(bn * 128 + row) * K_PAD + c * 8;
    }
    const int ldsbase = wave * 512;   // wave-uniform element base (+l*2048)

#define STAGE(buf, kt)                                                        \
    do {                                                                      \
        _Pragma("unroll")                                                     \
        for (int l = 0; l < 2; ++l) {                                         \
            __builtin_amdgcn_global_load_lds(                                 \
                (const __attribute__((address_space(1))) void*)(srcA[l] + (kt) * 32), \
                (__attribute__((address_space(3))) void*)(As + (buf) * 4096 + l * 2048 + ldsbase), \
                16, 0, 0);                                                    \
            __builtin_amdgcn_global_load_lds(                                 \
                (const __attribute__((address_space(1))) void*)(srcB[l] + (kt) * 32), \
                (__attribute__((address_space(3))) void*)(Bs + (buf) * 4096 + l * 2048 + ldsbase), \
                16, 0, 0);                                                    \
        }                                                                     \
    } while (0)

    const int col  = lane & 15;
    const int quad = lane >> 4;
    const int swz  = quad ^ ((col >> 1) & 3);
    int aoff[4], boff[4];
    #pragma unroll
    for (int i = 0; i < 4; ++i)
        aoff[i] = (wm * 64 + i * 16 + col) * 32 + swz * 8;
    #pragma unroll
    for (int j = 0; j < 4; ++j)
        boff[j] = (wn * 64 + j * 16 + col) * 32 + swz * 8;

    f32x4 acc[4][4];
    #pragma unroll
    for (int i = 0; i < 4; ++i)
        #pragma unroll
        for (int j = 0; j < 4; ++j)
            acc[i][j] = (f32x4){0.f, 0.f, 0.f, 0.f};

#define COMPUTE(buf)                                                          \
    do {                                                                      \
        const __bf16* Ab = As + (buf) * 4096;                                 \
        const __bf16* Bb = Bs + (buf) * 4096;                                 \
        bf16x8 av[4], bv[4];                                                  \
        _Pragma("unroll")                                                     \
        for (int i = 0; i < 4; ++i) av[i] = *(const bf16x8*)(Ab + aoff[i]);   \
        _Pragma("unroll")                                                     \
        for (int j = 0; j < 4; ++j) bv[j] = *(const bf16x8*)(Bb + boff[j]);   \
        _Pragma("unroll")                                                     \
        for (int i = 0; i < 4; ++i)                                           \
            _Pragma("unroll")                                                 \
            for (int j = 0; j < 4; ++j)                                       \
                acc[i][j] = __builtin_amdgcn_mfma_f32_16x16x32_bf16(          \
                                av[i], bv[j], acc[i][j], 0, 0, 0);            \
    } while (0)

    // prologue: stage tile 0 into buf0 (compiler drains vmcnt before barrier)
    STAGE(0, 0);
    __syncthreads();

    for (int kt = 0; kt < NKT; kt += 2) {
        STAGE(1, kt + 1);                 // kt+1 <= 33 always valid
        COMPUTE(0);
        __syncthreads();
        if (kt + 2 < NKT) STAGE(0, kt + 2);
        COMPUTE(1);
        __syncthreads();
    }

    // epilogue: hidden = relu(acc + b1[n]); logits partial = hidden @ w2^T
    float bias[4], w20[4], w21[4], w22[4];
    #pragma unroll
    for (int ni = 0; ni < 4; ++ni) {
        int n = bn * 128 + wn * 64 + ni * 16 + col;
        bool v = n < F_REAL;   // padded rows have acc==0 anyway
        bias[ni] = v ? b1[n] : 0.0f;
        w20[ni]  = v ? w2[n] : 0.0f;
        w21[ni]  = v ? w2[F_REAL + n] : 0.0f;
        w22[ni]  = v ? w2[2 * F_REAL + n] : 0.0f;
    }
    #pragma unroll
    for (int mi = 0; mi < 4; ++mi) {
        float c0[4] = {0,0,0,0}, c1[4] = {0,0,0,0}, c2[4] = {0,0,0,0};
        #pragma unroll
        for (int ni = 0; ni < 4; ++ni) {
            #pragma unroll
            for (int r = 0; r < 4; ++r) {
                float hd = fmaxf(acc[mi][ni][r] + bias[ni], 0.0f);
                c0[r] += hd * w20[ni];
                c1[r] += hd * w21[ni];
                c2[r] += hd * w22[ni];
            }
        }
        #pragma unroll
        for (int m = 8; m >= 1; m >>= 1) {
            #pragma unroll
            for (int r = 0; r < 4; ++r) {
                c0[r] += __shfl_xor(c0[r], m, 64);
                c1[r] += __shfl_xor(c1[r], m, 64);
                c2[r] += __shfl_xor(c2[r], m, 64);
            }
        }
        if (col == 0) {
            int gm = bm * 128 + wm * 64 + mi * 16 + quad * 4;
            #pragma unroll
            for (int r = 0; r < 4; ++r) {
                atomicAdd(out + (size_t)(gm + r) * 3 + 0, c0[r]);
                atomicAdd(out + (size_t)(gm + r) * 3 + 1, c1[r]);
                atomicAdd(out + (size_t)(gm + r) * 3 + 2, c2[r]);
            }
        }
    }
#undef STAGE
#undef COMPUTE
}

extern "C" void kernel_launch(void* const* d_in, const int* in_sizes, int n_in,
                              void* d_out, int out_size, void* d_ws, size_t ws_size,
                              hipStream_t stream)
{
    const float* h  = (const float*)d_in[0];
    const float* vp = (const float*)d_in[1];
    const float* vh = (const float*)d_in[2];
    const float* nd = (const float*)d_in[3];
    const float* ns = (const float*)d_in[4];
    const float* w1 = (const float*)d_in[5];
    const float* b1 = (const float*)d_in[6];
    const float* w2 = (const float*)d_in[7];
    const float* b2 = (const float*)d_in[8];
    float* out = (float*)d_out;

    u16* Afull = (u16*)d_ws;                              // [16384][1088] bf16
    u16* Bfull = Afull + (size_t)B_ROWS * K_PAD;          // [1152][1088]  bf16

    prep_kernel<<<1024, 256, 0, stream>>>(h, vp, vh, nd, ns, Afull);
    convw_kernel<<<N_PAD, 256, 0, stream>>>(w1, Bfull);
    initout_kernel<<<(B_ROWS * 3 + 255) / 256, 256, 0, stream>>>(b2, out);
    gemm_kernel<<<dim3(B_ROWS / 128, N_PAD / 128), 256, 0, stream>>>(
        Afull, Bfull, b1, w2, out);
}